// Round 2
// 706.223 us; speedup vs baseline: 1.0112x; 1.0112x over previous
//
#include <hip/hip_runtime.h>
#include <hip/hip_fp16.h>

// SpikingLinear on MI355X:
//   lin = input[:-1] @ W^T   (M=32512, N=1024, K=1024)  via split-fp16 MFMA:
//     A = Ah + Al, W = Wh + Wl  (fp16 RTN hi + fp16 residual lo)
//     lin ~= Ah*Wh + Ah*Wl + Al*Wh   (3x mfma_f32_16x16x32_f16, fp32 acc)
//   sigma(lin) ~ 1e-7 (vs 2.7e-6 bf16 3-pass which passed at absmax 2.78;
//   1-pass fp16 sigma 3.2e-4 FAILED at 7.69 > 4.52 -> 3 passes are mandatory).
//   Then per-(b,o) temporal scan (syn/mem/spk), in-place in the output buffer.
//
// GEMM grid is XCD-locality remapped: 8 n-tiles of each m-panel run
// consecutively on ONE XCD (lin%8 = bx), so the 512KB A-panel is an L2 hit
// for 7/8 of its reads (was: 8x HBM re-fetch = 1.06 GB of A traffic).
//
// Buffer reuse (no d_ws): Ah/Al (133.2MB) in the spk-output plane, Wh/Wl
// (4MB) in the V-output plane. GEMM writes lin into the I-output plane at
// step t+1. Scan overwrites everything afterwards. Serialized on `stream`.

#define STEPS 128
#define BATCH 256
#define DIN   1024
#define DOUT  1024

#define ALPHA 0.7788007830714049f   // exp(-1/4)
#define BETA  0.9512294245007140f   // exp(-1/20)

constexpr int    GM      = (STEPS - 1) * BATCH;        // 32512 GEMM rows
constexpr size_t PLANE   = (size_t)BATCH * DOUT;       // 262144 elems / step
constexpr size_t A_ELEMS = (size_t)GM * DIN;           // 33,292,288
constexpr size_t W_ELEMS = (size_t)DOUT * DIN;         // 1,048,576

typedef __attribute__((ext_vector_type(8))) _Float16 half8;   // 8 fp16 = 4 VGPR
typedef __attribute__((ext_vector_type(4))) float float4v;    // MFMA C/D

// ---------------------------------------------------------------- split ----
__global__ __launch_bounds__(256)
void split_kernel(const float* __restrict__ x,
                  unsigned short* __restrict__ hi,
                  unsigned short* __restrict__ lo)
{
    const size_t i = (size_t)blockIdx.x * 256 + threadIdx.x;   // float4 index
    const float4 v = reinterpret_cast<const float4*>(x)[i];
    float f[4] = {v.x, v.y, v.z, v.w};
    unsigned short hb[4], lb[4];
#pragma unroll
    for (int j = 0; j < 4; ++j) {
        _Float16 h = (_Float16)f[j];                       // RTN
        _Float16 l = (_Float16)(f[j] - (float)h);          // exact residual, RTN
        hb[j] = *reinterpret_cast<unsigned short*>(&h);
        lb[j] = *reinterpret_cast<unsigned short*>(&l);
    }
    ushort4 hv = {hb[0], hb[1], hb[2], hb[3]};
    ushort4 lv = {lb[0], lb[1], lb[2], lb[3]};
    reinterpret_cast<ushort4*>(hi)[i] = hv;
    reinterpret_cast<ushort4*>(lo)[i] = lv;
}

// ----------------------------------------------------------------- gemm ----
__device__ __forceinline__ void load16(const unsigned short* g, unsigned short* l)
{
    __builtin_amdgcn_global_load_lds(
        (const __attribute__((address_space(1))) void*)g,
        (__attribute__((address_space(3))) void*)l, 16, 0, 0);
}

__global__ __launch_bounds__(256)
void gemm_kernel(const unsigned short* __restrict__ Ah,
                 const unsigned short* __restrict__ Al,
                 const unsigned short* __restrict__ Wh,
                 const unsigned short* __restrict__ Wl,
                 float* __restrict__ C)
{
    // XCD-locality remap: grid is (8, 256); linear dispatch id = by*8 + bx,
    // so lin%8 = bx -> all by for a given bx land on one XCD (round-robin).
    // That XCD sweeps m-panels [bx*32, bx*32+32), n-inner: 8 consecutive
    // blocks share one A-panel -> L2 hit.
    const int mt = blockIdx.x * 32 + (blockIdx.y >> 3);    // 0..255
    const int nt = blockIdx.y & 7;                         // 0..7
    if (mt >= GM / 128) return;                            // 254 real m-tiles
    const int m0 = mt * 128;
    const int n0 = nt * 128;

    // 4 arrays x 128 rows x 32 k fp16 = 4 x 8KB = 32 KB
    __shared__ __align__(16) unsigned short smem[4 * 4096];

    const int t    = threadIdx.x;
    const int wave = t >> 6, lane = t & 63;

    // staging: row-major [128][32]; pass p covers rows p*64..p*64+63
    const int srow = t >> 2, skg = t & 3;
    const size_t offA = (size_t)(m0 + srow) * DIN + skg * 8;
    const size_t offB = (size_t)(n0 + srow) * DIN + skg * 8;
    unsigned short* lds0 = smem + (size_t)(wave * 64) * 8;         // pass 0 dest
    unsigned short* lds1 = smem + (size_t)(256 + wave * 64) * 8;   // pass 1 dest

    const int wr = wave >> 1, wc = wave & 1;   // wave -> 64x64 quadrant
    const int lr = lane & 15, q = lane >> 4;

    float4v acc[4][4];
#pragma unroll
    for (int i = 0; i < 4; ++i)
#pragma unroll
        for (int j = 0; j < 4; ++j)
            acc[i][j] = (float4v){0.f, 0.f, 0.f, 0.f};

    for (int k0 = 0; k0 < DIN; k0 += 32) {
        const unsigned short* pAh = Ah + offA + k0;
        const unsigned short* pAl = Al + offA + k0;
        const unsigned short* pBh = Wh + offB + k0;
        const unsigned short* pBl = Wl + offB + k0;
        load16(pAh,            lds0);
        load16(pAh + 64 * DIN, lds1);
        load16(pAl,            lds0 + 4096);
        load16(pAl + 64 * DIN, lds1 + 4096);
        load16(pBh,            lds0 + 8192);
        load16(pBh + 64 * DIN, lds1 + 8192);
        load16(pBl,            lds0 + 12288);
        load16(pBl + 64 * DIN, lds1 + 12288);
        __syncthreads();   // compiler drains vmcnt before s_barrier

        half8 ah[4], al[4], bh[4], bl[4];
#pragma unroll
        for (int i = 0; i < 4; ++i) {
            const int r = wr * 64 + i * 16 + lr;
            ah[i] = *reinterpret_cast<const half8*>(smem +        r * 32 + q * 8);
            al[i] = *reinterpret_cast<const half8*>(smem + 4096 + r * 32 + q * 8);
        }
#pragma unroll
        for (int j = 0; j < 4; ++j) {
            const int r = wc * 64 + j * 16 + lr;
            bh[j] = *reinterpret_cast<const half8*>(smem + 8192  + r * 32 + q * 8);
            bl[j] = *reinterpret_cast<const half8*>(smem + 12288 + r * 32 + q * 8);
        }
#pragma unroll
        for (int i = 0; i < 4; ++i)
#pragma unroll
            for (int j = 0; j < 4; ++j) {
                acc[i][j] = __builtin_amdgcn_mfma_f32_16x16x32_f16(ah[i], bh[j], acc[i][j], 0, 0, 0);
                acc[i][j] = __builtin_amdgcn_mfma_f32_16x16x32_f16(ah[i], bl[j], acc[i][j], 0, 0, 0);
                acc[i][j] = __builtin_amdgcn_mfma_f32_16x16x32_f16(al[i], bh[j], acc[i][j], 0, 0, 0);
            }
        __syncthreads();
    }

    // C/D layout: col = lane&15, row = (lane>>4)*4 + reg   [m89/m91 verified]
#pragma unroll
    for (int i = 0; i < 4; ++i) {
        const int mrow = m0 + wr * 64 + i * 16 + q * 4;
#pragma unroll
        for (int j = 0; j < 4; ++j) {
            const int ncol = n0 + wc * 64 + j * 16 + lr;
#pragma unroll
            for (int rg = 0; rg < 4; ++rg)
                C[(size_t)(mrow + rg) * DOUT + ncol] = acc[i][j][rg];
        }
    }
}

// ----------------------------------------------------------------- scan ----
__global__ __launch_bounds__(256)
void scan_kernel(float* __restrict__ out)
{
    const int idx = blockIdx.x * 256 + threadIdx.x;   // (b,o) flat
    float* o0 = out;                                   // spk
    float* o1 = out + STEPS * PLANE;                   // V
    float* o2 = out + 2 * STEPS * PLANE;               // I (holds lin at t>=1)

    __builtin_nontemporal_store(0.0f, &o0[idx]);
    __builtin_nontemporal_store(0.0f, &o1[idx]);
    __builtin_nontemporal_store(0.0f, &o2[idx]);

    // depth-3 prefetch of lin reads
    float n1 = o2[idx + PLANE];
    float n2 = o2[idx + 2 * PLANE];
    float n3 = o2[idx + 3 * PLANE];

    float syn = 0.0f, mem = 0.0f;
    size_t off = idx;
    for (int i = 1; i < STEPS; ++i) {
        off += PLANE;
        const float cur = n1; n1 = n2; n2 = n3;
        if (i + 3 < STEPS) n3 = o2[off + 3 * PLANE];
        const float reset = (mem > 1.0f) ? 1.0f : 0.0f;
        syn = ALPHA * syn + cur;
        mem = (BETA * mem + syn) * (1.0f - reset);
        const float spk = (mem > 1.0f) ? 1.0f : 0.0f;
        __builtin_nontemporal_store(spk, &o0[off]);
        __builtin_nontemporal_store(mem, &o1[off]);
        __builtin_nontemporal_store(syn, &o2[off]);
    }
}

// --------------------------------------------------------------- launch ----
extern "C" void kernel_launch(void* const* d_in, const int* in_sizes, int n_in,
                              void* d_out, int out_size, void* d_ws, size_t ws_size,
                              hipStream_t stream)
{
    const float* input  = (const float*)d_in[0];   // [128, 256, 1024]
    const float* weight = (const float*)d_in[1];   // [1024, 1024]
    float* out = (float*)d_out;

    unsigned short* Ah = (unsigned short*)out;                     // spk plane
    unsigned short* Al = Ah + A_ELEMS;                             // 133.2MB < 134.2MB
    unsigned short* Wh = (unsigned short*)(out + STEPS * PLANE);   // V plane
    unsigned short* Wl = Wh + W_ELEMS;
    float* lin = out + 2 * STEPS * PLANE + PLANE;                  // I plane, t>=1

    split_kernel<<<(int)(A_ELEMS / 1024), 256, 0, stream>>>(input, Ah, Al);
    split_kernel<<<(int)(W_ELEMS / 1024), 256, 0, stream>>>(weight, Wh, Wl);

    gemm_kernel<<<dim3(8, 256), 256, 0, stream>>>(Ah, Al, Wh, Wl, lin);

    scan_kernel<<<(int)(PLANE / 256), 256, 0, stream>>>(out);
}

// Round 3
// 690.202 us; speedup vs baseline: 1.0347x; 1.0232x over previous
//
#include <hip/hip_runtime.h>
#include <hip/hip_fp16.h>

// SpikingLinear on MI355X:
//   lin = input[:-1] @ W^T   (M=32512, N=1024, K=1024)  via split-fp16 MFMA:
//     A = Ah + Al, W = Wh + Wl  (fp16 RTN hi + fp16 residual lo)
//     lin ~= Ah*Wh + Al*Wh + Ah*Wl   (3 passes, fp32 acc)  == virtual K=3072 GEMM
//   GEMM: 256x256 tile, BK=32, 4-deep LDS ring, counted vmcnt(8) (never 0),
//   XOR-swizzled LDS reads (2-way = free), setprio around MFMA cluster,
//   32 MFMA per barrier (AITER-style).  8 waves = 2M x 4N, 128x64 per wave.
//   Then per-(b,o) temporal scan (syn/mem/spk), in-place in the output buffer.
//
// Buffer reuse (no d_ws): Ah/Al (133.2MB) in the spk-output plane, Wh/Wl
// (4MB) in the V-output plane. GEMM writes lin into the I-output plane at
// step t+1. Scan overwrites everything afterwards. Serialized on `stream`.

#define STEPS 128
#define BATCH 256
#define DIN   1024
#define DOUT  1024

#define ALPHA 0.7788007830714049f   // exp(-1/4)
#define BETA  0.9512294245007140f   // exp(-1/20)

constexpr int    GM      = (STEPS - 1) * BATCH;        // 32512 GEMM rows
constexpr size_t PLANE   = (size_t)BATCH * DOUT;       // 262144 elems / step
constexpr size_t A_ELEMS = (size_t)GM * DIN;           // 33,292,288
constexpr size_t W_ELEMS = (size_t)DOUT * DIN;         // 1,048,576

constexpr int NKT = 96;   // virtual K tiles: 3 passes x (1024/32)

typedef __attribute__((ext_vector_type(8))) _Float16 half8;   // 8 fp16 = 4 VGPR
typedef __attribute__((ext_vector_type(4))) float float4v;    // MFMA C/D

// ---------------------------------------------------------------- split ----
__global__ __launch_bounds__(256)
void split_kernel(const float* __restrict__ x,
                  unsigned short* __restrict__ hi,
                  unsigned short* __restrict__ lo)
{
    const size_t i = (size_t)blockIdx.x * 256 + threadIdx.x;   // float4 index
    const float4 v = reinterpret_cast<const float4*>(x)[i];
    float f[4] = {v.x, v.y, v.z, v.w};
    unsigned short hb[4], lb[4];
#pragma unroll
    for (int j = 0; j < 4; ++j) {
        _Float16 h = (_Float16)f[j];                       // RTN
        _Float16 l = (_Float16)(f[j] - (float)h);          // exact residual, RTN
        hb[j] = *reinterpret_cast<unsigned short*>(&h);
        lb[j] = *reinterpret_cast<unsigned short*>(&l);
    }
    ushort4 hv = {hb[0], hb[1], hb[2], hb[3]};
    ushort4 lv = {lb[0], lb[1], lb[2], lb[3]};
    reinterpret_cast<ushort4*>(hi)[i] = hv;
    reinterpret_cast<ushort4*>(lo)[i] = lv;
}

// ----------------------------------------------------------------- gemm ----
__device__ __forceinline__ void load16(const unsigned short* g, unsigned short* l)
{
    __builtin_amdgcn_global_load_lds(
        (const __attribute__((address_space(1))) void*)g,
        (__attribute__((address_space(3))) void*)l, 16, 0, 0);
}

__global__ __launch_bounds__(512, 2)
void gemm_kernel(const unsigned short* __restrict__ Ah,
                 const unsigned short* __restrict__ Al,
                 const unsigned short* __restrict__ Wh,
                 const unsigned short* __restrict__ Wl,
                 float* __restrict__ C)
{
    // LDS ring: A: 4 bufs x 256x32 fp16 (16KB) at 0; B: same at 32768 (ushorts)
    __shared__ __align__(16) unsigned short smem[65536];   // 128 KiB

    // XCD-chunked 1D grid (512 blocks): xcd = lin%8 owns 16 m-panels; the 4
    // n-tiles of a panel are consecutive -> concurrent on one XCD (A in L2).
    const int lin = blockIdx.x;
    const int xcd = lin & 7, slot = lin >> 3;          // slot 0..63
    const int mp  = xcd * 16 + (slot >> 2);            // m-panel 0..127
    const int nt  = slot & 3;
    if (mp >= GM / 256) return;                        // 127 real panels
    const int m0 = mp * 256;
    const int n0 = nt * 256;

    const int t = threadIdx.x;
    const int w = t >> 6, l = t & 63;
    const int wr = w >> 2, wc = w & 3;                 // 2M x 4N waves
    const int lr = l & 15, q = l >> 4;

    // T2 swizzle: LDS(row, g) holds global 16B-granule g ^ ((row>>1)&3).
    // Read side: granule index is lane-only: g = q ^ ((l>>1)&3)  (bits 1-2 of
    // row == bits 1-2 of lr; higher row bits don't reach the XOR).
    const int swz = q ^ ((l >> 1) & 3);

    // per-lane LDS read offsets (ushort units), sans ring-buffer base
    const int laneA = (wr * 128 + lr) * 32 + swz * 8;
    const int laneB = (wc * 64  + lr) * 32 + swz * 8;

    // staging: wave w, call c covers LDS rows w*32+c*16 .. +16 (64 granules,
    // linear dest).  Source is inverse-swizzled per lane (rule #21):
    //   row = w*32+c*16 + (l>>2), src granule = (l&3) ^ ((l>>3)&3)
    const int srow = l >> 2;
    const int sg   = ((l & 3) ^ ((l >> 3) & 3)) * 8;   // ushort offset

    const size_t sA0 = (size_t)(m0 + w * 32 +      srow) * DIN + sg;
    const size_t sA1 = (size_t)(m0 + w * 32 + 16 + srow) * DIN + sg;
    const size_t sB0 = (size_t)(n0 + w * 32 +      srow) * DIN + sg;
    const size_t sB1 = (size_t)(n0 + w * 32 + 16 + srow) * DIN + sg;

    unsigned short* dA0 = smem + w * 1024;             // (w*2+0)*512 ushorts
    unsigned short* dA1 = smem + w * 1024 + 512;
    unsigned short* dB0 = smem + 32768 + w * 1024;
    unsigned short* dB1 = smem + 32768 + w * 1024 + 512;

    // stage virtual K-tile ks into ring slot ks&3 (4 loads/thread)
    auto STAGE = [&](int ks) {
        const int p  = ks >> 5;                        // pass 0/1/2
        const int kk = (ks & 31) << 5;                 // k0 within 1024
        const unsigned short* sa = (p == 1) ? Al : Ah;
        const unsigned short* sw = (p == 2) ? Wl : Wh;
        const int bo = (ks & 3) * 8192;
        load16(sa + sA0 + kk, dA0 + bo);
        load16(sa + sA1 + kk, dA1 + bo);
        load16(sw + sB0 + kk, dB0 + bo);
        load16(sw + sB1 + kk, dB1 + bo);
    };

    float4v acc[8][4];
#pragma unroll
    for (int m = 0; m < 8; ++m)
#pragma unroll
        for (int n = 0; n < 4; ++n)
            acc[m][n] = (float4v){0.f, 0.f, 0.f, 0.f};

    // prologue: 3 tiles in flight (12 loads); tile 0 ready after vmcnt(8)
    STAGE(0); STAGE(1); STAGE(2);
    asm volatile("s_waitcnt vmcnt(8)" ::: "memory");
    __builtin_amdgcn_s_barrier();

    // Ledger: tile t's 4 loads are issue #[4t+1..4t+4].  Block kt stages tile
    // kt+3 then waits vmcnt(8): issued through 4(kt+4), so tiles <= kt+1 are
    // complete -- exactly what block kt+1 reads.  Never drains to 0 (T4).
    for (int kt = 0; kt < NKT; ++kt) {
        const int bo = (kt & 3) * 8192;
        const unsigned short* pA = smem + bo + laneA;
        const unsigned short* pB = smem + 32768 + bo + laneB;

        half8 a[8], b[4];
#pragma unroll
        for (int m = 0; m < 8; ++m)
            a[m] = *reinterpret_cast<const half8*>(pA + m * 512);
#pragma unroll
        for (int n = 0; n < 4; ++n)
            b[n] = *reinterpret_cast<const half8*>(pB + n * 512);

        int ks = kt + 3;
        if (ks >= NKT) ks -= NKT;   // wrapped dummy stages keep ledger uniform
        STAGE(ks);

        __builtin_amdgcn_s_setprio(1);
#pragma unroll
        for (int m = 0; m < 8; ++m)
#pragma unroll
            for (int n = 0; n < 4; ++n)
                acc[m][n] = __builtin_amdgcn_mfma_f32_16x16x32_f16(
                    a[m], b[n], acc[m][n], 0, 0, 0);
        __builtin_amdgcn_s_setprio(0);

        asm volatile("s_waitcnt vmcnt(8)" ::: "memory");
        __builtin_amdgcn_s_barrier();
    }

    // C/D layout: col = lane&15, row = (lane>>4)*4 + reg   [m89/m91 verified]
    const int mw = m0 + wr * 128 + q * 4;
    const int nw = n0 + wc * 64 + lr;
#pragma unroll
    for (int m = 0; m < 8; ++m)
#pragma unroll
        for (int n = 0; n < 4; ++n)
#pragma unroll
            for (int rg = 0; rg < 4; ++rg)
                C[(size_t)(mw + m * 16 + rg) * DOUT + (nw + n * 16)] = acc[m][n][rg];
}

// ----------------------------------------------------------------- scan ----
__global__ __launch_bounds__(256)
void scan_kernel(float* __restrict__ out)
{
    const int idx = blockIdx.x * 256 + threadIdx.x;   // (b,o) flat
    float* o0 = out;                                   // spk
    float* o1 = out + STEPS * PLANE;                   // V
    float* o2 = out + 2 * STEPS * PLANE;               // I (holds lin at t>=1)

    __builtin_nontemporal_store(0.0f, &o0[idx]);
    __builtin_nontemporal_store(0.0f, &o1[idx]);
    __builtin_nontemporal_store(0.0f, &o2[idx]);

    // depth-3 prefetch of lin reads
    float n1 = o2[idx + PLANE];
    float n2 = o2[idx + 2 * PLANE];
    float n3 = o2[idx + 3 * PLANE];

    float syn = 0.0f, mem = 0.0f;
    size_t off = idx;
    for (int i = 1; i < STEPS; ++i) {
        off += PLANE;
        const float cur = n1; n1 = n2; n2 = n3;
        if (i + 3 < STEPS) n3 = o2[off + 3 * PLANE];
        const float reset = (mem > 1.0f) ? 1.0f : 0.0f;
        syn = ALPHA * syn + cur;
        mem = (BETA * mem + syn) * (1.0f - reset);
        const float spk = (mem > 1.0f) ? 1.0f : 0.0f;
        __builtin_nontemporal_store(spk, &o0[off]);
        __builtin_nontemporal_store(mem, &o1[off]);
        __builtin_nontemporal_store(syn, &o2[off]);
    }
}

// --------------------------------------------------------------- launch ----
extern "C" void kernel_launch(void* const* d_in, const int* in_sizes, int n_in,
                              void* d_out, int out_size, void* d_ws, size_t ws_size,
                              hipStream_t stream)
{
    const float* input  = (const float*)d_in[0];   // [128, 256, 1024]
    const float* weight = (const float*)d_in[1];   // [1024, 1024]
    float* out = (float*)d_out;

    unsigned short* Ah = (unsigned short*)out;                     // spk plane
    unsigned short* Al = Ah + A_ELEMS;                             // 133.2MB < 134.2MB
    unsigned short* Wh = (unsigned short*)(out + STEPS * PLANE);   // V plane
    unsigned short* Wl = Wh + W_ELEMS;
    float* lin = out + 2 * STEPS * PLANE + PLANE;                  // I plane, t>=1

    split_kernel<<<(int)(A_ELEMS / 1024), 256, 0, stream>>>(input, Ah, Al);
    split_kernel<<<(int)(W_ELEMS / 1024), 256, 0, stream>>>(weight, Wh, Wl);

    gemm_kernel<<<512, 512, 0, stream>>>(Ah, Al, Wh, Wl, lin);

    scan_kernel<<<(int)(PLANE / 256), 256, 0, stream>>>(out);
}

// Round 4
// 686.457 us; speedup vs baseline: 1.0404x; 1.0055x over previous
//
#include <hip/hip_runtime.h>
#include <hip/hip_fp16.h>

// SpikingLinear on MI355X:
//   lin = input[:-1] @ W^T   (M=32512, N=1024, K=1024)  via split-fp16 MFMA:
//     A = Ah + Al, W = Wh + Wl  (fp16 RTN hi + fp16 residual lo)
//     lin ~= Ah*Wh + Ah*Wl + Al*Wh   (3 passes, fp32 acc)
//   GEMM v3: 256x256 tile, BK=32, ring-2 LDS x 4 arrays (128 KiB), 4-array
//   staging so B-frags stay IN REGISTERS across the 3 passes (24 ds_read +
//   8 DMA per 96 wave-MFMAs, vs 36+12 for virtual-K), 3 read||MFMA sub-phases
//   per tile (inline-asm ds_read_b128 + lgkmcnt(0) + sched_barrier so the
//   compiler cannot insert conservative vmcnt drains), setprio(1) around each
//   32-MFMA cluster, stage-issue at tile top + single LATE vmcnt(0) per tile
//   (~930cy of MFMA covers the DMA latency; drain is free).
//   8 waves = 2M x 4N, 128x64 per wave.  1 block/CU (128KB LDS).
//   Then per-(b,o) temporal scan (syn/mem/spk), in-place in the output buffer.
//
// Buffer reuse (no d_ws): Ah/Al (133.2MB) in the spk-output plane, Wh/Wl
// (4MB) in the V-output plane. GEMM writes lin into the I-output plane at
// step t+1. Scan overwrites everything afterwards. Serialized on `stream`.

#define STEPS 128
#define BATCH 256
#define DIN   1024
#define DOUT  1024

#define ALPHA 0.7788007830714049f   // exp(-1/4)
#define BETA  0.9512294245007140f   // exp(-1/20)

constexpr int    GM      = (STEPS - 1) * BATCH;        // 32512 GEMM rows
constexpr size_t PLANE   = (size_t)BATCH * DOUT;       // 262144 elems / step
constexpr size_t A_ELEMS = (size_t)GM * DIN;           // 33,292,288
constexpr size_t W_ELEMS = (size_t)DOUT * DIN;         // 1,048,576

typedef __attribute__((ext_vector_type(8))) _Float16 half8;   // 8 fp16 = 4 VGPR
typedef __attribute__((ext_vector_type(4))) float float4v;    // MFMA C/D

// ---------------------------------------------------------------- split ----
__global__ __launch_bounds__(256)
void split_kernel(const float* __restrict__ x,
                  unsigned short* __restrict__ hi,
                  unsigned short* __restrict__ lo)
{
    const size_t i = (size_t)blockIdx.x * 256 + threadIdx.x;   // float4 index
    const float4 v = reinterpret_cast<const float4*>(x)[i];
    float f[4] = {v.x, v.y, v.z, v.w};
    unsigned short hb[4], lb[4];
#pragma unroll
    for (int j = 0; j < 4; ++j) {
        _Float16 h = (_Float16)f[j];                       // RTN
        _Float16 l = (_Float16)(f[j] - (float)h);          // exact residual, RTN
        hb[j] = *reinterpret_cast<unsigned short*>(&h);
        lb[j] = *reinterpret_cast<unsigned short*>(&l);
    }
    ushort4 hv = {hb[0], hb[1], hb[2], hb[3]};
    ushort4 lv = {lb[0], lb[1], lb[2], lb[3]};
    reinterpret_cast<ushort4*>(hi)[i] = hv;
    reinterpret_cast<ushort4*>(lo)[i] = lv;
}

// ----------------------------------------------------------------- gemm ----
__device__ __forceinline__ void load16(const unsigned short* g, unsigned short* l)
{
    __builtin_amdgcn_global_load_lds(
        (const __attribute__((address_space(1))) void*)g,
        (__attribute__((address_space(3))) void*)l, 16, 0, 0);
}

// inline-asm LDS read: addr is a byte offset into the (single) LDS block.
__device__ __forceinline__ half8 ldsr(unsigned addr)
{
    half8 r;
    asm volatile("ds_read_b128 %0, %1" : "=v"(r) : "v"(addr) : "memory");
    return r;
}

__global__ __launch_bounds__(512, 2)
void gemm_kernel(const unsigned short* __restrict__ Ah,
                 const unsigned short* __restrict__ Al,
                 const unsigned short* __restrict__ Wh,
                 const unsigned short* __restrict__ Wl,
                 float* __restrict__ C)
{
    // ring-2 slots of 64 KiB: {Ah 16KB | Al 16KB | Bh 16KB | Bl 16KB},
    // each array 256 rows x 32 k fp16 (row = 64 B).
    __shared__ __align__(16) unsigned short smem[65536];   // 128 KiB

    // XCD-chunked 1D grid (512 blocks): xcd = lin%8 owns 16 m-panels; the 4
    // n-tiles of a panel are consecutive -> concurrent on one XCD (A in L2).
    const int lin = blockIdx.x;
    const int xcd = lin & 7, slot = lin >> 3;          // slot 0..63
    const int mp  = xcd * 16 + (slot >> 2);            // m-panel
    const int nt  = slot & 3;
    if (mp >= GM / 256) return;                        // 127 real panels
    const int m0 = mp * 256;
    const int n0 = nt * 256;

    const int t = threadIdx.x;
    const int w = t >> 6, l = t & 63;
    const int wr = w >> 2, wc = w & 3;                 // 2M x 4N waves
    const int lr = l & 15, q = l >> 4;

    // T2 swizzle (proven in R3): LDS(row,g) holds global granule g^((row>>1)&3);
    // read-side granule = q ^ ((l>>1)&3) (row bits 1-2 == lr bits 1-2).
    const int swz = q ^ ((l >> 1) & 3);

    // byte read-address bases within a slot (+ m/n*1024, + 16384 for lo array)
    const unsigned rdA = (unsigned)((wr * 128 + lr) * 64 + swz * 16);
    const unsigned rdB = (unsigned)(32768 + (wc * 64 + lr) * 64 + swz * 16);

    // staging (linear LDS dest, inverse-swizzled global source; rule #21):
    // wave w covers rows w*32 + (l>>2) (+16 for the second call) of each array.
    const int srow = l >> 2;
    const int sg   = ((l & 3) ^ ((l >> 3) & 3)) * 8;   // ushort offset

    const size_t sA0 = (size_t)(m0 + w * 32 +      srow) * DIN + sg;
    const size_t sA1 = (size_t)(m0 + w * 32 + 16 + srow) * DIN + sg;
    const size_t sB0 = (size_t)(n0 + w * 32 +      srow) * DIN + sg;
    const size_t sB1 = (size_t)(n0 + w * 32 + 16 + srow) * DIN + sg;

    // stage K-tile ks (8 gload_lds per thread) into ring slot ks&1
    auto STAGE = [&](int ks) {
        const int kk = (ks & 31) << 5;                 // k0 within 1024
        unsigned short* d = smem + ((ks & 1) << 15) + w * 1024;
        load16(Ah + sA0 + kk, d);
        load16(Ah + sA1 + kk, d + 512);
        load16(Al + sA0 + kk, d + 8192);
        load16(Al + sA1 + kk, d + 8704);
        load16(Wh + sB0 + kk, d + 16384);
        load16(Wh + sB1 + kk, d + 16896);
        load16(Wl + sB0 + kk, d + 24576);
        load16(Wl + sB1 + kk, d + 25088);
    };

    float4v acc[8][4];
#pragma unroll
    for (int m = 0; m < 8; ++m)
#pragma unroll
        for (int n = 0; n < 4; ++n)
            acc[m][n] = (float4v){0.f, 0.f, 0.f, 0.f};

    // prologue: tile 0 staged and complete (drain is outside the loop, once)
    STAGE(0);
    asm volatile("s_waitcnt vmcnt(0)" ::: "memory");
    __builtin_amdgcn_s_barrier();

    for (int kt = 0; kt < 32; ++kt) {
        const unsigned sb = (unsigned)((kt & 1) << 16);   // slot byte base

        // issue next tile's DMA first: ~930cy of MFMA below covers its latency
        STAGE((kt + 1) & 31);   // kt=31 wraps to a dummy re-stage of tile 0

        half8 ah[8], bh[4], bl[4];

        // ---- phase 0: Ah x Bh -------------------------------------------
#pragma unroll
        for (int m = 0; m < 8; ++m) ah[m] = ldsr(sb + rdA + m * 1024);
#pragma unroll
        for (int n = 0; n < 4; ++n) bh[n] = ldsr(sb + rdB + n * 1024);
        asm volatile("s_waitcnt lgkmcnt(0)" ::: "memory");
        __builtin_amdgcn_sched_barrier(0);
        __builtin_amdgcn_s_setprio(1);
#pragma unroll
        for (int m = 0; m < 8; ++m)
#pragma unroll
            for (int n = 0; n < 4; ++n)
                acc[m][n] = __builtin_amdgcn_mfma_f32_16x16x32_f16(
                    ah[m], bh[n], acc[m][n], 0, 0, 0);
        __builtin_amdgcn_s_setprio(0);

        // ---- phase 1: Ah x Bl (ah reused from regs) ---------------------
#pragma unroll
        for (int n = 0; n < 4; ++n) bl[n] = ldsr(sb + rdB + 16384 + n * 1024);
        asm volatile("s_waitcnt lgkmcnt(0)" ::: "memory");
        __builtin_amdgcn_sched_barrier(0);
        __builtin_amdgcn_s_setprio(1);
#pragma unroll
        for (int m = 0; m < 8; ++m)
#pragma unroll
            for (int n = 0; n < 4; ++n)
                acc[m][n] = __builtin_amdgcn_mfma_f32_16x16x32_f16(
                    ah[m], bl[n], acc[m][n], 0, 0, 0);
        __builtin_amdgcn_s_setprio(0);

        // ---- phase 2: Al x Bh (al overwrites ah regs; bh reused) --------
#pragma unroll
        for (int m = 0; m < 8; ++m) ah[m] = ldsr(sb + rdA + 16384 + m * 1024);
        asm volatile("s_waitcnt lgkmcnt(0)" ::: "memory");
        __builtin_amdgcn_sched_barrier(0);
        __builtin_amdgcn_s_setprio(1);
#pragma unroll
        for (int m = 0; m < 8; ++m)
#pragma unroll
            for (int n = 0; n < 4; ++n)
                acc[m][n] = __builtin_amdgcn_mfma_f32_16x16x32_f16(
                    ah[m], bh[n], acc[m][n], 0, 0, 0);
        __builtin_amdgcn_s_setprio(0);

        // late drain: DMA issued at tile top has had the whole tile to land
        asm volatile("s_waitcnt vmcnt(0)" ::: "memory");
        __builtin_amdgcn_s_barrier();
    }

    // C/D layout: col = lane&15, row = (lane>>4)*4 + reg   [m89/m91 verified]
    const int mw = m0 + wr * 128 + q * 4;
    const int nw = n0 + wc * 64 + lr;
#pragma unroll
    for (int m = 0; m < 8; ++m)
#pragma unroll
        for (int n = 0; n < 4; ++n)
#pragma unroll
            for (int rg = 0; rg < 4; ++rg)
                C[(size_t)(mw + m * 16 + rg) * DOUT + (nw + n * 16)] = acc[m][n][rg];
}

// ----------------------------------------------------------------- scan ----
__global__ __launch_bounds__(256)
void scan_kernel(float* __restrict__ out)
{
    const int idx = blockIdx.x * 256 + threadIdx.x;   // (b,o) flat
    float* o0 = out;                                   // spk
    float* o1 = out + STEPS * PLANE;                   // V
    float* o2 = out + 2 * STEPS * PLANE;               // I (holds lin at t>=1)

    __builtin_nontemporal_store(0.0f, &o0[idx]);
    __builtin_nontemporal_store(0.0f, &o1[idx]);
    __builtin_nontemporal_store(0.0f, &o2[idx]);

    // depth-3 prefetch of lin reads
    float n1 = o2[idx + PLANE];
    float n2 = o2[idx + 2 * PLANE];
    float n3 = o2[idx + 3 * PLANE];

    float syn = 0.0f, mem = 0.0f;
    size_t off = idx;
    for (int i = 1; i < STEPS; ++i) {
        off += PLANE;
        const float cur = n1; n1 = n2; n2 = n3;
        if (i + 3 < STEPS) n3 = o2[off + 3 * PLANE];
        const float reset = (mem > 1.0f) ? 1.0f : 0.0f;
        syn = ALPHA * syn + cur;
        mem = (BETA * mem + syn) * (1.0f - reset);
        const float spk = (mem > 1.0f) ? 1.0f : 0.0f;
        __builtin_nontemporal_store(spk, &o0[off]);
        __builtin_nontemporal_store(mem, &o1[off]);
        __builtin_nontemporal_store(syn, &o2[off]);
    }
}

// --------------------------------------------------------------- launch ----
extern "C" void kernel_launch(void* const* d_in, const int* in_sizes, int n_in,
                              void* d_out, int out_size, void* d_ws, size_t ws_size,
                              hipStream_t stream)
{
    const float* input  = (const float*)d_in[0];   // [128, 256, 1024]
    const float* weight = (const float*)d_in[1];   // [1024, 1024]
    float* out = (float*)d_out;

    unsigned short* Ah = (unsigned short*)out;                     // spk plane
    unsigned short* Al = Ah + A_ELEMS;                             // 133.2MB < 134.2MB
    unsigned short* Wh = (unsigned short*)(out + STEPS * PLANE);   // V plane
    unsigned short* Wl = Wh + W_ELEMS;
    float* lin = out + 2 * STEPS * PLANE + PLANE;                  // I plane, t>=1

    split_kernel<<<(int)(A_ELEMS / 1024), 256, 0, stream>>>(input, Ah, Al);
    split_kernel<<<(int)(W_ELEMS / 1024), 256, 0, stream>>>(weight, Wh, Wl);

    gemm_kernel<<<512, 512, 0, stream>>>(Ah, Al, Wh, Wl, lin);

    scan_kernel<<<(int)(PLANE / 256), 256, 0, stream>>>(out);
}

// Round 5
// 682.886 us; speedup vs baseline: 1.0458x; 1.0052x over previous
//
#include <hip/hip_runtime.h>
#include <hip/hip_fp16.h>

// SpikingLinear on MI355X:
//   lin = input[:-1] @ W^T   (M=32512, N=1024, K=1024)  via split-fp16 MFMA:
//     A = Ah + Al, W = Wh + Wl  (fp16 RTN hi + fp16 residual lo)
//     lin ~= Ah*Wh + Ah*Wl + Al*Wh   (3 passes, fp32 acc)
//   GEMM v4: faithful 8-phase-template port (m201):
//     256x256 tile, BK=32, 2x64KB LDS slots, SIX phases per K-tile, each
//     {ds_read subtile || stage-issue -> s_barrier -> lgkmcnt(0)+sched_barrier
//      -> setprio(1) 16xMFMA setprio(0) -> s_barrier},
//     half-tile staging H1={Ah,Wh}@P0 / H2={Al,Wl}@P2 with COUNTED vmcnt(4)
//     at P1/P5 ends -- never drains to 0 in the main loop (T4; m218).
//   8 waves = 2M x 4N, 128x64 per wave.  1 block/CU (128KB LDS).
//   Per-acc add order (hh,hl,lh) identical to R2-R4 -> absmax canary 1.96875.
//   Then per-(b,o) temporal scan (syn/mem/spk), in-place in the output buffer.
//
// Buffer reuse (no d_ws): Ah/Al (133.2MB) in the spk-output plane, Wh/Wl
// (4MB) in the V-output plane. GEMM writes lin into the I-output plane at
// step t+1. Scan overwrites everything afterwards. Serialized on `stream`.

#define STEPS 128
#define BATCH 256
#define DIN   1024
#define DOUT  1024

#define ALPHA 0.7788007830714049f   // exp(-1/4)
#define BETA  0.9512294245007140f   // exp(-1/20)

constexpr int    GM      = (STEPS - 1) * BATCH;        // 32512 GEMM rows
constexpr size_t PLANE   = (size_t)BATCH * DOUT;       // 262144 elems / step
constexpr size_t A_ELEMS = (size_t)GM * DIN;           // 33,292,288
constexpr size_t W_ELEMS = (size_t)DOUT * DIN;         // 1,048,576

typedef __attribute__((ext_vector_type(8))) _Float16 half8;   // 8 fp16 = 4 VGPR
typedef __attribute__((ext_vector_type(4))) float float4v;    // MFMA C/D

// ---------------------------------------------------------------- split ----
__global__ __launch_bounds__(256)
void split_kernel(const float* __restrict__ x,
                  unsigned short* __restrict__ hi,
                  unsigned short* __restrict__ lo)
{
    const size_t i = (size_t)blockIdx.x * 256 + threadIdx.x;   // float4 index
    const float4 v = reinterpret_cast<const float4*>(x)[i];
    float f[4] = {v.x, v.y, v.z, v.w};
    unsigned short hb[4], lb[4];
#pragma unroll
    for (int j = 0; j < 4; ++j) {
        _Float16 h = (_Float16)f[j];                       // RTN
        _Float16 l = (_Float16)(f[j] - (float)h);          // exact residual, RTN
        hb[j] = *reinterpret_cast<unsigned short*>(&h);
        lb[j] = *reinterpret_cast<unsigned short*>(&l);
    }
    ushort4 hv = {hb[0], hb[1], hb[2], hb[3]};
    ushort4 lv = {lb[0], lb[1], lb[2], lb[3]};
    reinterpret_cast<ushort4*>(hi)[i] = hv;
    reinterpret_cast<ushort4*>(lo)[i] = lv;
}

// ----------------------------------------------------------------- gemm ----
__device__ __forceinline__ void load16(const unsigned short* g, unsigned short* l)
{
    __builtin_amdgcn_global_load_lds(
        (const __attribute__((address_space(1))) void*)g,
        (__attribute__((address_space(3))) void*)l, 16, 0, 0);
}

// inline-asm LDS read: addr is a byte offset into the (single) LDS block.
__device__ __forceinline__ half8 ldsr(unsigned addr)
{
    half8 r;
    asm volatile("ds_read_b128 %0, %1" : "=v"(r) : "v"(addr) : "memory");
    return r;
}

// phase boilerplate: leading barrier + lgkmcnt(0) (rule #18: sched_barrier
// right after), MFMA cluster wrapped in setprio, trailing sched pin.
#define PHASE_PRE() do {                                        \
    __builtin_amdgcn_s_barrier();                               \
    asm volatile("s_waitcnt lgkmcnt(0)" ::: "memory");          \
    __builtin_amdgcn_sched_barrier(0);                          \
    __builtin_amdgcn_s_setprio(1);                              \
} while (0)

#define PHASE_POST() do {                                       \
    __builtin_amdgcn_s_setprio(0);                              \
    __builtin_amdgcn_sched_barrier(0);                          \
    __builtin_amdgcn_s_barrier();                               \
} while (0)

#define PHASE_POST_VM4() do {                                   \
    __builtin_amdgcn_s_setprio(0);                              \
    __builtin_amdgcn_sched_barrier(0);                          \
    asm volatile("s_waitcnt vmcnt(4)" ::: "memory");            \
    __builtin_amdgcn_s_barrier();                               \
} while (0)

#define MFMA_BLK(MB, BV)                                        \
    _Pragma("unroll")                                           \
    for (int mm = 0; mm < 4; ++mm)                              \
        _Pragma("unroll")                                       \
        for (int nn = 0; nn < 4; ++nn)                          \
            acc[(MB) + mm][nn] = __builtin_amdgcn_mfma_f32_16x16x32_f16( \
                ah[(MB) + mm], BV[nn], acc[(MB) + mm][nn], 0, 0, 0)

__global__ __launch_bounds__(512, 2)
void gemm_kernel(const unsigned short* __restrict__ Ah,
                 const unsigned short* __restrict__ Al,
                 const unsigned short* __restrict__ Wh,
                 const unsigned short* __restrict__ Wl,
                 float* __restrict__ C)
{
    // 2 slots of 64 KiB: {Ah 16KB | Al 16KB | Bh 16KB | Bl 16KB},
    // each array 256 rows x 32 k fp16 (row = 64 B).
    __shared__ __align__(16) unsigned short smem[65536];   // 128 KiB

    // XCD-chunked 1D grid (512 blocks): xcd = lin%8 owns 16 m-panels; the 4
    // n-tiles of a panel are consecutive -> concurrent on one XCD (A in L2).
    const int lin = blockIdx.x;
    const int xcd = lin & 7, slot = lin >> 3;          // slot 0..63
    const int mp  = xcd * 16 + (slot >> 2);            // m-panel
    const int nt  = slot & 3;
    if (mp >= GM / 256) return;                        // 127 real panels
    const int m0 = mp * 256;
    const int n0 = nt * 256;

    const int t = threadIdx.x;
    const int w = t >> 6, l = t & 63;
    const int wr = w >> 2, wc = w & 3;                 // 2M x 4N waves
    const int lr = l & 15, q = l >> 4;

    // T2 swizzle (proven R3/R4): LDS(row,g) holds global granule g^((row>>1)&3);
    // read-side granule = q ^ ((l>>1)&3) (row bits 1-2 == lr bits 1-2).
    const int swz = q ^ ((l >> 1) & 3);

    // byte read-address bases within a slot (+ m/n*1024, + 16384 for lo array)
    const unsigned rdA = (unsigned)((wr * 128 + lr) * 64 + swz * 16);
    const unsigned rdB = (unsigned)(32768 + (wc * 64 + lr) * 64 + swz * 16);

    // staging (linear LDS dest, inverse-swizzled global source; rule #21):
    // wave w covers rows w*32 + (l>>2) (+16 for the second call) of each array.
    const int srow = l >> 2;
    const int sg   = ((l & 3) ^ ((l >> 3) & 3)) * 8;   // ushort offset

    const size_t sA0 = (size_t)(m0 + w * 32 +      srow) * DIN + sg;
    const size_t sA1 = (size_t)(m0 + w * 32 + 16 + srow) * DIN + sg;
    const size_t sB0 = (size_t)(n0 + w * 32 +      srow) * DIN + sg;
    const size_t sB1 = (size_t)(n0 + w * 32 + 16 + srow) * DIN + sg;

    // half-tile stages into slot ks&1 (4 loads/thread each).
    // H1 = {Ah, Wh} (consumed at P0 of tile ks); H2 = {Al, Wl} (at P2).
    auto STAGE_H1 = [&](int ks) {
        const int kk = (ks & 31) << 5;
        unsigned short* d = smem + ((ks & 1) << 15) + w * 1024;
        load16(Ah + sA0 + kk, d);
        load16(Ah + sA1 + kk, d + 512);
        load16(Wh + sB0 + kk, d + 16384);
        load16(Wh + sB1 + kk, d + 16896);
    };
    auto STAGE_H2 = [&](int ks) {
        const int kk = (ks & 31) << 5;
        unsigned short* d = smem + ((ks & 1) << 15) + w * 1024;
        load16(Al + sA0 + kk, d + 8192);
        load16(Al + sA1 + kk, d + 8704);
        load16(Wl + sB0 + kk, d + 24576);
        load16(Wl + sB1 + kk, d + 25088);
    };

    float4v acc[8][4];
#pragma unroll
    for (int m = 0; m < 8; ++m)
#pragma unroll
        for (int n = 0; n < 4; ++n)
            acc[m][n] = (float4v){0.f, 0.f, 0.f, 0.f};

    // prologue: stage tile 0 (both halves); vmcnt(4) completes H1(0) only,
    // H2(0) stays in flight -- steady-state ledger holds from tile 0.
    STAGE_H1(0);
    STAGE_H2(0);
    asm volatile("s_waitcnt vmcnt(4)" ::: "memory");
    __builtin_amdgcn_s_barrier();

    // Per-wave vmcnt ledger (4 loads per half-tile stage):
    //   end P5 of tile t: in flight [H1(t+1), H2(t+1)] -> vmcnt(4) => H1 done.
    //   end P1 of tile t: in flight [H2(t),   H1(t+1)] -> vmcnt(4) => H2 done.
    // Never 0 in the loop.  kt=31 wrap-stages tile 0 (dummy, keeps ledger).
    for (int kt = 0; kt < 32; ++kt) {
        const unsigned sb = (unsigned)((kt & 1) << 16);   // slot byte base
        half8 ah[8], bh[4], bl[4];

        // ---- P0: ah[0:4], bh[0:4]; stage H1(t+1); MFMA m0-3 x bh ---------
#pragma unroll
        for (int m = 0; m < 4; ++m) ah[m] = ldsr(sb + rdA + m * 1024);
#pragma unroll
        for (int n = 0; n < 4; ++n) bh[n] = ldsr(sb + rdB + n * 1024);
        STAGE_H1((kt + 1) & 31);
        PHASE_PRE();  MFMA_BLK(0, bh);  PHASE_POST();

        // ---- P1: ah[4:8]; MFMA m4-7 x bh; vmcnt(4) => H2(t) landed -------
#pragma unroll
        for (int m = 4; m < 8; ++m) ah[m] = ldsr(sb + rdA + m * 1024);
        PHASE_PRE();  MFMA_BLK(4, bh);  PHASE_POST_VM4();

        // ---- P2: bl[0:4]; stage H2(t+1); MFMA m0-3 x bl ------------------
#pragma unroll
        for (int n = 0; n < 4; ++n) bl[n] = ldsr(sb + rdB + 16384 + n * 1024);
        STAGE_H2((kt + 1) & 31);
        PHASE_PRE();  MFMA_BLK(0, bl);  PHASE_POST();

        // ---- P3: al[0:4] -> ah[0:4]; MFMA m4-7 x bl ----------------------
#pragma unroll
        for (int m = 0; m < 4; ++m) ah[m] = ldsr(sb + rdA + 16384 + m * 1024);
        PHASE_PRE();  MFMA_BLK(4, bl);  PHASE_POST();

        // ---- P4: al[4:8] -> ah[4:8]; MFMA m0-3 (=al) x bh ----------------
#pragma unroll
        for (int m = 4; m < 8; ++m) ah[m] = ldsr(sb + rdA + 16384 + m * 1024);
        PHASE_PRE();  MFMA_BLK(0, bh);  PHASE_POST();

        // ---- P5: MFMA m4-7 (=al) x bh; vmcnt(4) => H1(t+1) landed --------
        PHASE_PRE();  MFMA_BLK(4, bh);  PHASE_POST_VM4();
    }

    // C/D layout: col = lane&15, row = (lane>>4)*4 + reg   [m89/m91 verified]
    const int mw = m0 + wr * 128 + q * 4;
    const int nw = n0 + wc * 64 + lr;
#pragma unroll
    for (int m = 0; m < 8; ++m)
#pragma unroll
        for (int n = 0; n < 4; ++n)
#pragma unroll
            for (int rg = 0; rg < 4; ++rg)
                C[(size_t)(mw + m * 16 + rg) * DOUT + (nw + n * 16)] = acc[m][n][rg];
}

// ----------------------------------------------------------------- scan ----
__global__ __launch_bounds__(256)
void scan_kernel(float* __restrict__ out)
{
    const int idx = blockIdx.x * 256 + threadIdx.x;   // (b,o) flat
    float* o0 = out;                                   // spk
    float* o1 = out + STEPS * PLANE;                   // V
    float* o2 = out + 2 * STEPS * PLANE;               // I (holds lin at t>=1)

    __builtin_nontemporal_store(0.0f, &o0[idx]);
    __builtin_nontemporal_store(0.0f, &o1[idx]);
    __builtin_nontemporal_store(0.0f, &o2[idx]);

    // depth-3 prefetch of lin reads
    float n1 = o2[idx + PLANE];
    float n2 = o2[idx + 2 * PLANE];
    float n3 = o2[idx + 3 * PLANE];

    float syn = 0.0f, mem = 0.0f;
    size_t off = idx;
    for (int i = 1; i < STEPS; ++i) {
        off += PLANE;
        const float cur = n1; n1 = n2; n2 = n3;
        if (i + 3 < STEPS) n3 = o2[off + 3 * PLANE];
        const float reset = (mem > 1.0f) ? 1.0f : 0.0f;
        syn = ALPHA * syn + cur;
        mem = (BETA * mem + syn) * (1.0f - reset);
        const float spk = (mem > 1.0f) ? 1.0f : 0.0f;
        __builtin_nontemporal_store(spk, &o0[off]);
        __builtin_nontemporal_store(mem, &o1[off]);
        __builtin_nontemporal_store(syn, &o2[off]);
    }
}

// --------------------------------------------------------------- launch ----
extern "C" void kernel_launch(void* const* d_in, const int* in_sizes, int n_in,
                              void* d_out, int out_size, void* d_ws, size_t ws_size,
                              hipStream_t stream)
{
    const float* input  = (const float*)d_in[0];   // [128, 256, 1024]
    const float* weight = (const float*)d_in[1];   // [1024, 1024]
    float* out = (float*)d_out;

    unsigned short* Ah = (unsigned short*)out;                     // spk plane
    unsigned short* Al = Ah + A_ELEMS;                             // 133.2MB < 134.2MB
    unsigned short* Wh = (unsigned short*)(out + STEPS * PLANE);   // V plane
    unsigned short* Wl = Wh + W_ELEMS;
    float* lin = out + 2 * STEPS * PLANE + PLANE;                  // I plane, t>=1

    split_kernel<<<(int)(A_ELEMS / 1024), 256, 0, stream>>>(input, Ah, Al);
    split_kernel<<<(int)(W_ELEMS / 1024), 256, 0, stream>>>(weight, Wh, Wl);

    gemm_kernel<<<512, 512, 0, stream>>>(Ah, Al, Wh, Wl, lin);

    scan_kernel<<<(int)(PLANE / 256), 256, 0, stream>>>(out);
}

// Round 6
// 629.671 us; speedup vs baseline: 1.1342x; 1.0845x over previous
//
#include <hip/hip_runtime.h>
#include <hip/hip_fp16.h>

// SpikingLinear on MI355X:
//   lin = input[:-1] @ W^T   (M=32512, N=1024, K=1024)  via split-fp16 MFMA:
//     A = Ah + Al, W = Wh + Wl  (fp16 RTN hi + fp16 residual lo)
//     lin ~= Ah*Wh + Ah*Wl + Al*Wh   (3 passes, fp32 acc)
//   GEMM v5: R5's 6-phase skeleton, but the A-SPLIT IS FUSED INTO STAGING:
//     the GEMM reads A as f32 (same bytes as the fp16 pair), converts to
//     hi/lo in registers and ds_writes the identical LDS image.  This
//     removes the split-A kernel's 266 MB HBM round-trip (~45 us).
//     T14: f32 loads issued at P0 (5-phase lead), cvt+ds_write at P5 end
//     (compiler's auto vmcnt(4) = write-late); W via global_load_lds staged
//     at P2, drained at end-of-tile BEFORE the barrier (cross-wave-safe,
//     ~2000cy after issue -> no stall).
//   8 waves = 2M x 4N, 128x64 per wave.  1 block/CU (128KB LDS).
//   Conversion math + MFMA order bit-identical to R5 -> absmax canary 1.96875.
//   Then per-(b,o) temporal scan (syn/mem/spk), in-place in the output buffer.
//
// Buffer reuse (no d_ws): Wh/Wl (4MB) in the V-output plane.  GEMM writes lin
// into the I-output plane at step t+1.  Scan overwrites everything afterwards.
// All kernels serialized on `stream`.

#define STEPS 128
#define BATCH 256
#define DIN   1024
#define DOUT  1024

#define ALPHA 0.7788007830714049f   // exp(-1/4)
#define BETA  0.9512294245007140f   // exp(-1/20)

constexpr int    GM      = (STEPS - 1) * BATCH;        // 32512 GEMM rows
constexpr size_t PLANE   = (size_t)BATCH * DOUT;       // 262144 elems / step
constexpr size_t W_ELEMS = (size_t)DOUT * DIN;         // 1,048,576

typedef __attribute__((ext_vector_type(8))) _Float16 half8;   // 8 fp16 = 4 VGPR
typedef __attribute__((ext_vector_type(4))) float float4v;    // MFMA C/D

// ---------------------------------------------------------------- split ----
// (W only now -- 4 MB, ~2 us)
__global__ __launch_bounds__(256)
void split_kernel(const float* __restrict__ x,
                  unsigned short* __restrict__ hi,
                  unsigned short* __restrict__ lo)
{
    const size_t i = (size_t)blockIdx.x * 256 + threadIdx.x;   // float4 index
    const float4 v = reinterpret_cast<const float4*>(x)[i];
    float f[4] = {v.x, v.y, v.z, v.w};
    unsigned short hb[4], lb[4];
#pragma unroll
    for (int j = 0; j < 4; ++j) {
        _Float16 h = (_Float16)f[j];                       // RTN
        _Float16 l = (_Float16)(f[j] - (float)h);          // exact residual, RTN
        hb[j] = *reinterpret_cast<unsigned short*>(&h);
        lb[j] = *reinterpret_cast<unsigned short*>(&l);
    }
    ushort4 hv = {hb[0], hb[1], hb[2], hb[3]};
    ushort4 lv = {lb[0], lb[1], lb[2], lb[3]};
    reinterpret_cast<ushort4*>(hi)[i] = hv;
    reinterpret_cast<ushort4*>(lo)[i] = lv;
}

// ----------------------------------------------------------------- gemm ----
__device__ __forceinline__ void load16(const unsigned short* g, unsigned short* l)
{
    __builtin_amdgcn_global_load_lds(
        (const __attribute__((address_space(1))) void*)g,
        (__attribute__((address_space(3))) void*)l, 16, 0, 0);
}

// inline-asm LDS read: addr is a byte offset into the (single) LDS block.
__device__ __forceinline__ half8 ldsr(unsigned addr)
{
    half8 r;
    asm volatile("ds_read_b128 %0, %1" : "=v"(r) : "v"(addr) : "memory");
    return r;
}

#define PHASE_PRE() do {                                        \
    __builtin_amdgcn_s_barrier();                               \
    asm volatile("s_waitcnt lgkmcnt(0)" ::: "memory");          \
    __builtin_amdgcn_sched_barrier(0);                          \
    __builtin_amdgcn_s_setprio(1);                              \
} while (0)

#define PHASE_POST() do {                                       \
    __builtin_amdgcn_s_setprio(0);                              \
    __builtin_amdgcn_sched_barrier(0);                          \
    __builtin_amdgcn_s_barrier();                               \
} while (0)

#define MFMA_BLK(MB, BV)                                        \
    _Pragma("unroll")                                           \
    for (int mm = 0; mm < 4; ++mm)                              \
        _Pragma("unroll")                                       \
        for (int nn = 0; nn < 4; ++nn)                          \
            acc[(MB) + mm][nn] = __builtin_amdgcn_mfma_f32_16x16x32_f16( \
                ah[(MB) + mm], BV[nn], acc[(MB) + mm][nn], 0, 0, 0)

__global__ __launch_bounds__(512, 2)
void gemm_kernel(const float* __restrict__ Af,
                 const unsigned short* __restrict__ Wh,
                 const unsigned short* __restrict__ Wl,
                 float* __restrict__ C)
{
    // 2 slots of 64 KiB: {Ah 16KB | Al 16KB | Bh 16KB | Bl 16KB},
    // each array 256 rows x 32 k fp16 (row = 64 B).
    __shared__ __align__(16) unsigned short smem[65536];   // 128 KiB

    // XCD-chunked 1D grid (512 blocks): xcd = lin%8 owns 16 m-panels; the 4
    // n-tiles of a panel are consecutive -> concurrent on one XCD (A in L2).
    const int lin = blockIdx.x;
    const int xcd = lin & 7, slot = lin >> 3;          // slot 0..63
    const int mp  = xcd * 16 + (slot >> 2);            // m-panel
    const int nt  = slot & 3;
    if (mp >= GM / 256) return;                        // 127 real panels
    const int m0 = mp * 256;
    const int n0 = nt * 256;

    const int t = threadIdx.x;
    const int w = t >> 6, l = t & 63;
    const int wr = w >> 2, wc = w & 3;                 // 2M x 4N waves
    const int lr = l & 15, q = l >> 4;

    // T2 swizzle (proven R3-R5): LDS(row,g) holds global granule g^(f(row));
    // read-side granule = q ^ ((l>>1)&3).
    const int swz = q ^ ((l >> 1) & 3);

    // byte read-address bases within a slot (+ m/n*1024, + 16384 for lo array)
    const unsigned rdA = (unsigned)((wr * 128 + lr) * 64 + swz * 16);
    const unsigned rdB = (unsigned)(32768 + (wc * 64 + lr) * 64 + swz * 16);

    // staging geometry (identical LDS image to R5):
    //   thread (w,l) owns dest granule (l&3) of rows w*32+(l>>2) and +16,
    //   sourced from global granule (l&3)^((l>>3)&3) of the same row.
    const int srow = l >> 2;
    const int sgE  = ((l & 3) ^ ((l >> 3) & 3)) * 8;   // element offset

    // A (f32 source, reg-staged)
    const size_t fA0 = (size_t)(m0 + w * 32 +      srow) * DIN + sgE;
    const size_t fA1 = (size_t)(m0 + w * 32 + 16 + srow) * DIN + sgE;
    // W (fp16 source, global_load_lds)
    const size_t sB0 = (size_t)(n0 + w * 32 +      srow) * DIN + sgE;
    const size_t sB1 = (size_t)(n0 + w * 32 + 16 + srow) * DIN + sgE;

    const unsigned dstA = (unsigned)(w * 1024 + l * 8);   // ushort idx in slot

    // stage W K-tile ks (4 gload_lds/thread) into slot ks&1
    auto STAGE_W = [&](int ks) {
        const int kk = (ks & 31) << 5;
        unsigned short* d = smem + ((ks & 1) << 15) + w * 1024;
        load16(Wh + sB0 + kk, d + 16384);
        load16(Wh + sB1 + kk, d + 16896);
        load16(Wl + sB0 + kk, d + 24576);
        load16(Wl + sB1 + kk, d + 25088);
    };

    // convert 8 f32 -> hi/lo half8 and write one granule pair
    auto WRITE_A = [&](float4 x, float4 y, unsigned short* ds, unsigned off) {
        float f[8] = {x.x, x.y, x.z, x.w, y.x, y.y, y.z, y.w};
        half8 h, lo8;
#pragma unroll
        for (int j = 0; j < 8; ++j) {
            _Float16 hh = (_Float16)f[j];              // RTN
            h[j]   = hh;
            lo8[j] = (_Float16)(f[j] - (float)hh);     // exact residual, RTN
        }
        *reinterpret_cast<half8*>(ds + dstA + off)        = h;
        *reinterpret_cast<half8*>(ds + dstA + off + 8192) = lo8;
    };

    float4v acc[8][4];
#pragma unroll
    for (int m = 0; m < 8; ++m)
#pragma unroll
        for (int n = 0; n < 4; ++n)
            acc[m][n] = (float4v){0.f, 0.f, 0.f, 0.f};

    // ---- prologue: build slot 0 (tile 0), full drain (one-time) ----------
    {
        float4 a0 = *reinterpret_cast<const float4*>(Af + fA0);
        float4 a1 = *reinterpret_cast<const float4*>(Af + fA0 + 4);
        float4 a2 = *reinterpret_cast<const float4*>(Af + fA1);
        float4 a3 = *reinterpret_cast<const float4*>(Af + fA1 + 4);
        STAGE_W(0);
        unsigned short* ds = smem;                      // slot 0
        WRITE_A(a0, a1, ds, 0);
        WRITE_A(a2, a3, ds, 512);
        asm volatile("s_waitcnt vmcnt(0) lgkmcnt(0)" ::: "memory");
        __builtin_amdgcn_s_barrier();
    }

    for (int kt = 0; kt < 32; ++kt) {
        const unsigned sb = (unsigned)((kt & 1) << 16);   // slot byte base
        const int kn = ((kt + 1) & 31) << 5;              // next tile k0
        half8 ah[8], bh[4], bl[4];

        // ---- P0: issue A(t+1) f32 loads (write-late at P5); ah/bh; MFMA --
        float4 a0 = *reinterpret_cast<const float4*>(Af + fA0 + kn);
        float4 a1 = *reinterpret_cast<const float4*>(Af + fA0 + kn + 4);
        float4 a2 = *reinterpret_cast<const float4*>(Af + fA1 + kn);
        float4 a3 = *reinterpret_cast<const float4*>(Af + fA1 + kn + 4);
#pragma unroll
        for (int m = 0; m < 4; ++m) ah[m] = ldsr(sb + rdA + m * 1024);
#pragma unroll
        for (int n = 0; n < 4; ++n) bh[n] = ldsr(sb + rdB + n * 1024);
        PHASE_PRE();  MFMA_BLK(0, bh);  PHASE_POST();

        // ---- P1: ah[4:8]; MFMA m4-7 x bh ---------------------------------
#pragma unroll
        for (int m = 4; m < 8; ++m) ah[m] = ldsr(sb + rdA + m * 1024);
        PHASE_PRE();  MFMA_BLK(4, bh);  PHASE_POST();

        // ---- P2: bl; stage W(t+1); MFMA m0-3 x bl ------------------------
#pragma unroll
        for (int n = 0; n < 4; ++n) bl[n] = ldsr(sb + rdB + 16384 + n * 1024);
        STAGE_W((kt + 1) & 31);
        PHASE_PRE();  MFMA_BLK(0, bl);  PHASE_POST();

        // ---- P3: al[0:4] -> ah; MFMA m4-7 x bl ---------------------------
#pragma unroll
        for (int m = 0; m < 4; ++m) ah[m] = ldsr(sb + rdA + 16384 + m * 1024);
        PHASE_PRE();  MFMA_BLK(4, bl);  PHASE_POST();

        // ---- P4: al[4:8] -> ah; MFMA m0-3 (=al) x bh ---------------------
#pragma unroll
        for (int m = 4; m < 8; ++m) ah[m] = ldsr(sb + rdA + 16384 + m * 1024);
        PHASE_PRE();  MFMA_BLK(0, bh);  PHASE_POST();

        // ---- P5: MFMA m4-7 (=al) x bh; cvt+ds_write A(t+1); tile drain ---
        PHASE_PRE();  MFMA_BLK(4, bh);
        __builtin_amdgcn_s_setprio(0);
        __builtin_amdgcn_sched_barrier(0);
        {
            unsigned short* ds = smem + (((kt + 1) & 1) << 15);
            WRITE_A(a0, a1, ds, 0);        // compiler auto-waits vmcnt here
            WRITE_A(a2, a3, ds, 512);
        }
        // W(t+1) issued 3 phases ago (~2000cy) -> this drain is already met;
        // lgkm drains our ds_writes; barrier makes slot t+1 cross-wave-valid.
        asm volatile("s_waitcnt vmcnt(0) lgkmcnt(0)" ::: "memory");
        __builtin_amdgcn_s_barrier();
    }

    // C/D layout: col = lane&15, row = (lane>>4)*4 + reg   [m89/m91 verified]
    const int mw = m0 + wr * 128 + q * 4;
    const int nw = n0 + wc * 64 + lr;
#pragma unroll
    for (int m = 0; m < 8; ++m)
#pragma unroll
        for (int n = 0; n < 4; ++n)
#pragma unroll
            for (int rg = 0; rg < 4; ++rg)
                C[(size_t)(mw + m * 16 + rg) * DOUT + (nw + n * 16)] = acc[m][n][rg];
}

// ----------------------------------------------------------------- scan ----
__global__ __launch_bounds__(256)
void scan_kernel(float* __restrict__ out)
{
    const int idx = blockIdx.x * 256 + threadIdx.x;   // (b,o) flat
    float* o0 = out;                                   // spk
    float* o1 = out + STEPS * PLANE;                   // V
    float* o2 = out + 2 * STEPS * PLANE;               // I (holds lin at t>=1)

    __builtin_nontemporal_store(0.0f, &o0[idx]);
    __builtin_nontemporal_store(0.0f, &o1[idx]);
    __builtin_nontemporal_store(0.0f, &o2[idx]);

    // depth-3 prefetch of lin reads
    float n1 = o2[idx + PLANE];
    float n2 = o2[idx + 2 * PLANE];
    float n3 = o2[idx + 3 * PLANE];

    float syn = 0.0f, mem = 0.0f;
    size_t off = idx;
    for (int i = 1; i < STEPS; ++i) {
        off += PLANE;
        const float cur = n1; n1 = n2; n2 = n3;
        if (i + 3 < STEPS) n3 = o2[off + 3 * PLANE];
        const float reset = (mem > 1.0f) ? 1.0f : 0.0f;
        syn = ALPHA * syn + cur;
        mem = (BETA * mem + syn) * (1.0f - reset);
        const float spk = (mem > 1.0f) ? 1.0f : 0.0f;
        __builtin_nontemporal_store(spk, &o0[off]);
        __builtin_nontemporal_store(mem, &o1[off]);
        __builtin_nontemporal_store(syn, &o2[off]);
    }
}

// --------------------------------------------------------------- launch ----
extern "C" void kernel_launch(void* const* d_in, const int* in_sizes, int n_in,
                              void* d_out, int out_size, void* d_ws, size_t ws_size,
                              hipStream_t stream)
{
    const float* input  = (const float*)d_in[0];   // [128, 256, 1024]
    const float* weight = (const float*)d_in[1];   // [1024, 1024]
    float* out = (float*)d_out;

    unsigned short* Wh = (unsigned short*)(out + STEPS * PLANE);   // V plane
    unsigned short* Wl = Wh + W_ELEMS;
    float* lin = out + 2 * STEPS * PLANE + PLANE;                  // I plane, t>=1

    split_kernel<<<(int)(W_ELEMS / 1024), 256, 0, stream>>>(weight, Wh, Wl);

    gemm_kernel<<<512, 512, 0, stream>>>(input, Wh, Wl, lin);

    scan_kernel<<<(int)(PLANE / 256), 256, 0, stream>>>(out);
}